// Round 4
// baseline (1033.819 us; speedup 1.0000x reference)
//
#include <hip/hip_runtime.h>
#include <hip/hip_bf16.h>
#include <cstdint>
#include <cstddef>

#define TT 8192
#define DD 1024
#define II 4096
#define EE 8
#define CAP 2560

#define BM 128
#define BN 128
#define BK 32   // bf16 elems per k-tile; row = 64 B, unpadded (global_load_lds layout)

typedef __attribute__((ext_vector_type(4))) float f32x4_t;
typedef __attribute__((ext_vector_type(8))) short bf16x8_t;

static __device__ __forceinline__ unsigned short f2bf(float f) {
    __hip_bfloat16 h = __float2bfloat16(f);
    return *reinterpret_cast<unsigned short*>(&h);
}

// branchless tanh-form gelu; max |diff| vs exact erf-gelu ~5e-4 (bf16-safe)
static __device__ __forceinline__ float gelu_fast(float x) {
    float y = 0.7978845608028654f * (x + 0.044715f * x * x * x);
    float a = fabsf(y);
    float e = __expf(2.0f * a);
    float t = 1.0f - 2.0f * __builtin_amdgcn_rcpf(e + 1.0f);   // tanh(|y|)
    t = copysignf(t, y);
    return 0.5f * x * (1.0f + t);
}

// async global->LDS, 16 B per lane; LDS dest = wave-uniform base + lane*16.
static __device__ __forceinline__ void gl_lds16(const void* g, void* l) {
    __builtin_amdgcn_global_load_lds(
        (__attribute__((address_space(1))) unsigned int*)g,
        (__attribute__((address_space(3))) unsigned int*)l, 16, 0, 0);
}

// ---------------------------------------------------------------------------
// fp32 -> bf16 flat convert (for x): 8 elems/thread.
// ---------------------------------------------------------------------------
__global__ __launch_bounds__(256) void cvt_x(
    const float* __restrict__ in, unsigned short* __restrict__ out) {
    int i = (blockIdx.x * 256 + threadIdx.x) * 8;
    float4 a = *(const float4*)(in + i);
    float4 b = *(const float4*)(in + i + 4);
    union { unsigned short s[8]; uint4 u; } pk;
    pk.s[0] = f2bf(a.x); pk.s[1] = f2bf(a.y); pk.s[2] = f2bf(a.z); pk.s[3] = f2bf(a.w);
    pk.s[4] = f2bf(b.x); pk.s[5] = f2bf(b.y); pk.s[6] = f2bf(b.z); pk.s[7] = f2bf(b.w);
    *(uint4*)(out + i) = pk.u;
}

// ---------------------------------------------------------------------------
// fp32 -> bf16 transposed copy: out[c*R + r] = bf16(in[r*C + c]), per batch z.
// ---------------------------------------------------------------------------
__global__ __launch_bounds__(256) void transpose_cvt(
    const float* __restrict__ in, unsigned short* __restrict__ out, int R, int C) {
    __shared__ float tile[32][33];
    size_t mb = (size_t)blockIdx.z * (size_t)R * (size_t)C;
    in += mb; out += mb;
    int cb = blockIdx.x * 32, rb = blockIdx.y * 32;
    int tx = threadIdx.x, ty = threadIdx.y;
#pragma unroll
    for (int j = 0; j < 4; ++j)
        tile[ty + j * 8][tx] = in[(size_t)(rb + ty + j * 8) * C + cb + tx];
    __syncthreads();
#pragma unroll
    for (int j = 0; j < 4; ++j)
        out[(size_t)(cb + ty + j * 8) * R + rb + tx] = f2bf(tile[tx][ty + j * 8]);
}

// ---------------------------------------------------------------------------
// Router: one wave per token. top-2; w0 = 1/(1+exp(l1-l0)) (= renorm softmax).
// ---------------------------------------------------------------------------
__global__ __launch_bounds__(256) void router_kernel(
    const float* __restrict__ x, const float* __restrict__ Wr,
    int* __restrict__ e0a, int* __restrict__ e1a,
    float* __restrict__ w0a, float* __restrict__ w1a) {
    int t = blockIdx.x * 4 + (threadIdx.x >> 6);
    int lane = threadIdx.x & 63;
    const float* xr = x + (size_t)t * DD;
    float acc[EE];
#pragma unroll
    for (int e = 0; e < EE; ++e) acc[e] = 0.f;
    for (int c = 0; c < DD; c += 64) {
        float xv = xr[c + lane];
#pragma unroll
        for (int e = 0; e < EE; ++e) acc[e] += xv * Wr[e * DD + c + lane];
    }
#pragma unroll
    for (int e = 0; e < EE; ++e) {
        float v = acc[e];
#pragma unroll
        for (int off = 32; off > 0; off >>= 1) v += __shfl_xor(v, off, 64);
        acc[e] = v;
    }
    if (lane == 0) {
        int b0 = 0; float m0 = acc[0];
#pragma unroll
        for (int e = 1; e < EE; ++e) if (acc[e] > m0) { m0 = acc[e]; b0 = e; }
        int b1 = -1; float m1 = -3.4e38f;
#pragma unroll
        for (int e = 0; e < EE; ++e) if (e != b0 && acc[e] > m1) { m1 = acc[e]; b1 = e; }
        float w0 = 1.f / (1.f + expf(m1 - m0));
        e0a[t] = b0; e1a[t] = b1; w0a[t] = w0; w1a[t] = 1.f - w0;
    }
}

// ---------------------------------------------------------------------------
// Assignment: single block, 1024 threads (16 waves), 8 tokens/thread (token
// order). Per expert: eligibility, block scan (wave shfl scan + wave-sum scan,
// 2 barriers), kept if pos<CAP else fallback. Mirrors reference semantics.
// ---------------------------------------------------------------------------
__global__ __launch_bounds__(1024) void assign_kernel(
    const int* __restrict__ e0a, const int* __restrict__ e1a,
    const float* __restrict__ w0a, const float* __restrict__ w1a,
    int* __restrict__ idxb, float* __restrict__ wslb,
    int* __restrict__ fbidx, int* __restrict__ counts) {
    __shared__ int wsum[16];
    __shared__ int ns[EE];
    const int t = threadIdx.x;
    const int lane = t & 63;
    const int wv = t >> 6;
    int e0v[8], e1v[8]; float w0v[8], w1v[8];
    bool fbv[8]; int sA[8], sB[8];
#pragma unroll
    for (int j = 0; j < 8; ++j) {
        int tok = t * 8 + j;
        e0v[j] = e0a[tok]; e1v[j] = e1a[tok];
        w0v[j] = w0a[tok]; w1v[j] = w1a[tok];
        fbv[j] = false; sA[j] = -1; sB[j] = -1;
    }
    for (int e = 0; e < EE; ++e) {
        int lp[8]; int c = 0; bool el[8];
#pragma unroll
        for (int j = 0; j < 8; ++j) {
            el[j] = (!fbv[j]) && (e0v[j] == e || e1v[j] == e);
            lp[j] = c; c += el[j] ? 1 : 0;
        }
        int incl = c;
#pragma unroll
        for (int off = 1; off < 64; off <<= 1) {
            int v = __shfl_up(incl, off, 64);
            if (lane >= off) incl += v;
        }
        if (lane == 63) wsum[wv] = incl;
        __syncthreads();
        int wbase = 0, total = 0;
#pragma unroll
        for (int u = 0; u < 16; ++u) {
            int v = wsum[u];
            total += v;
            if (u < wv) wbase += v;
        }
        int base = wbase + incl - c;
#pragma unroll
        for (int j = 0; j < 8; ++j) {
            if (el[j]) {
                int pos = base + lp[j];
                if (pos < CAP) {
                    int s = e * CAP + pos;
                    idxb[s] = t * 8 + j;
                    wslb[s] = (e0v[j] == e) ? w0v[j] : w1v[j];
                    if (sA[j] < 0) sA[j] = s; else sB[j] = s;
                } else {
                    fbv[j] = true;
                }
            }
        }
        if (t == 0) ns[e] = total < CAP ? total : CAP;
        __syncthreads();   // protects wsum reuse + publishes ns[e]
    }
    // pad unused slots (safe gather target token 0, weight 0)
    for (int s = t; s < EE * CAP; s += 1024) {
        int e = s / CAP, pos = s - e * CAP;
        if (pos >= ns[e]) { idxb[s] = 0; wslb[s] = 0.f; }
    }
    // tokens that fell back: zero their kept-slot weights
#pragma unroll
    for (int j = 0; j < 8; ++j) {
        if (fbv[j]) {
            if (sA[j] >= 0) wslb[sA[j]] = 0.f;
            if (sB[j] >= 0) wslb[sB[j]] = 0.f;
        }
    }
    // compact fallback token list
    int lp[8]; int c = 0;
#pragma unroll
    for (int j = 0; j < 8; ++j) { lp[j] = c; c += fbv[j] ? 1 : 0; }
    int incl = c;
#pragma unroll
    for (int off = 1; off < 64; off <<= 1) {
        int v = __shfl_up(incl, off, 64);
        if (lane >= off) incl += v;
    }
    if (lane == 63) wsum[wv] = incl;
    __syncthreads();
    int wbase = 0, total = 0;
#pragma unroll
    for (int u = 0; u < 16; ++u) {
        int v = wsum[u];
        total += v;
        if (u < wv) wbase += v;
    }
    int base = wbase + incl - c;
#pragma unroll
    for (int j = 0; j < 8; ++j)
        if (fbv[j]) fbidx[base + lp[j]] = t * 8 + j;
    for (int s = t; s < 4 * CAP; s += 1024)   // padded to 4*CAP (gather-safe)
        if (s >= total) fbidx[s] = 0;
    if (t == 0) {
        for (int e = 0; e < EE; ++e) counts[e] = ns[e];
        counts[EE] = total;
    }
}

// ---------------------------------------------------------------------------
// GEMM core: bf16 MFMA 16x16x32, 128x128 tile, BK=32, 256 threads (2x2 waves,
// 64x64/wave). Double-buffered LDS: prefetch tile it+1 via global_load_lds
// right after the barrier, compute tile it while it flies (one barrier/iter;
// the compiler's vmcnt(0)-before-barrier drains a load that had a full
// iteration to complete). LDS rows 64 B, k-chunk XOR swizzle as before.
// MFMA operands are SWAPPED (bfv, af) -> transposed C/D: lane holds output
// row = wm+i*16+l15, cols = wn+j*16+quad*4+{0..3} -> vectorized epilogue.
// MODE 0: expert GEMM1 (A = x_bf gathered via idxb) -> H = gelu(.+b1)
// MODE 1: expert GEMM2 (A = H) -> atomicAdd d_out += (.+b2)*w
// MODE 2: fallback GEMM1 (A = x_bf gathered via fbidx, chunk = z)
// MODE 3: fallback GEMM2 (A = H chunk z) -> d_out[tok] = .+fb2
// ---------------------------------------------------------------------------
template <int MODE>
__global__ __launch_bounds__(256) void gemm_kernel(
    const unsigned short* __restrict__ Abase,
    const unsigned short* __restrict__ Bt,
    const float* __restrict__ bias,
    unsigned short* __restrict__ Hout,
    float* __restrict__ dout,
    const int* __restrict__ idxp,
    const float* __restrict__ wslp,
    const int* __restrict__ counts,
    int e_base, int chunk_base) {
    constexpr bool IS_G1 = (MODE == 0 || MODE == 2);
    constexpr bool IS_EXPERT = (MODE == 0 || MODE == 1);
    constexpr int K = IS_G1 ? DD : II;

    const int z = blockIdx.z;
    const int e = e_base + z;               // expert modes
    const int ch0 = chunk_base + z * CAP;   // fallback modes
    const int m_base = blockIdx.x * BM;
    const int n_base = blockIdx.y * BN;

    const int cnt = IS_EXPERT ? counts[e] : counts[EE];
    if (IS_EXPERT) { if (m_base >= cnt) return; }
    else           { if (ch0 + m_base >= cnt) return; }

    __shared__ alignas(16) unsigned short As[2][BM * BK];
    __shared__ alignas(16) unsigned short Bs[2][BM * BK];

    const int tid = threadIdx.x;
    const int lane = tid & 63;
    const int wv = tid >> 6;
    const int wm = (wv & 1) * 64;
    const int wn = (wv >> 1) * 64;
    const int l15 = lane & 15;
    const int quad = lane >> 4;

    const unsigned short* BtE;
    if (MODE == 0)      BtE = Bt + (size_t)e * II * DD;
    else if (MODE == 1) BtE = Bt + (size_t)e * DD * II;
    else                BtE = Bt;

    // staging lane geometry: 16 rows x 64 B per wave-instruction
    const int lrow = lane >> 2;                        // tile row within 16
    const int kc = (lane & 3) ^ ((lrow >> 2) & 3);     // swizzled global k-chunk
    const unsigned short* aP[2];
    const unsigned short* bP[2];
#pragma unroll
    for (int p = 0; p < 2; ++p) {
        int r = wv * 32 + p * 16 + lrow;   // 0..127
        int slot = m_base + r;
        int arow;
        if (MODE == 0)      arow = idxp[e * CAP + slot];
        else if (MODE == 2) arow = idxp[ch0 + slot];
        else                arow = z * CAP + slot;     // H rows
        aP[p] = Abase + (size_t)arow * K + kc * 8;
        int nrow = n_base + r;
        bP[p] = BtE + (size_t)nrow * K + kc * 8;
    }
    unsigned short* lA[2][2]; unsigned short* lB[2][2];
#pragma unroll
    for (int b = 0; b < 2; ++b)
#pragma unroll
        for (int p = 0; p < 2; ++p) {
            lA[b][p] = &As[b][(wv * 32 + p * 16) * BK];
            lB[b][p] = &Bs[b][(wv * 32 + p * 16) * BK];
        }

    f32x4_t acc[4][4];
#pragma unroll
    for (int i = 0; i < 4; ++i)
#pragma unroll
        for (int j = 0; j < 4; ++j) acc[i][j] = (f32x4_t){0.f, 0.f, 0.f, 0.f};

    const int sw = (l15 >> 2) & 3;
    const int nit = K / BK;

    // prefetch tile 0 -> buffer 0
    gl_lds16(aP[0], lA[0][0]); gl_lds16(aP[1], lA[0][1]);
    gl_lds16(bP[0], lB[0][0]); gl_lds16(bP[1], lB[0][1]);
    aP[0] += BK; aP[1] += BK; bP[0] += BK; bP[1] += BK;

    for (int it = 0; it < nit; ++it) {
        __syncthreads();   // drains prefetch(it) — overlapped with compute(it-1)
        const int cb = it & 1;
        if (it + 1 < nit) {
            const int nb = cb ^ 1;
            gl_lds16(aP[0], lA[nb][0]); gl_lds16(aP[1], lA[nb][1]);
            gl_lds16(bP[0], lB[nb][0]); gl_lds16(bP[1], lB[nb][1]);
            aP[0] += BK; aP[1] += BK; bP[0] += BK; bP[1] += BK;
        }
        const unsigned short* Ab = As[cb];
        const unsigned short* Bb = Bs[cb];
        bf16x8_t af[4], bfv[4];
#pragma unroll
        for (int i = 0; i < 4; ++i)
            af[i] = *(const bf16x8_t*)&Ab[(wm + i * 16 + l15) * BK + ((quad ^ sw) * 8)];
#pragma unroll
        for (int j = 0; j < 4; ++j)
            bfv[j] = *(const bf16x8_t*)&Bb[(wn + j * 16 + l15) * BK + ((quad ^ sw) * 8)];
#pragma unroll
        for (int i = 0; i < 4; ++i)
#pragma unroll
            for (int j = 0; j < 4; ++j)
                acc[i][j] = __builtin_amdgcn_mfma_f32_16x16x32_bf16(
                    bfv[j], af[i], acc[i][j], 0, 0, 0);   // swapped -> C^T layout
    }

    // epilogue (transposed C): lane holds row = wm+i*16+l15,
    // cols = n_base+wn+j*16+quad*4+{0..3}
    const float* biasE;
    if (MODE == 0)      biasE = bias + (size_t)e * II;
    else if (MODE == 1) biasE = bias + (size_t)e * DD;
    else                biasE = bias;
#pragma unroll
    for (int i = 0; i < 4; ++i) {
        const int slot = m_base + wm + i * 16 + l15;
        int tok = 0; float w = 0.f; bool ok3 = false;
        if (MODE == 1) { w = wslp[e * CAP + slot]; tok = idxp[e * CAP + slot]; }
        if (MODE == 3) {
            int rg = ch0 + slot;
            ok3 = rg < cnt;
            tok = ok3 ? idxp[rg] : 0;
        }
#pragma unroll
        for (int j = 0; j < 4; ++j) {
            const int n0 = n_base + wn + j * 16 + quad * 4;
            float4 bv = *(const float4*)&biasE[n0];
            float v0 = acc[i][j][0] + bv.x;
            float v1 = acc[i][j][1] + bv.y;
            float v2 = acc[i][j][2] + bv.z;
            float v3 = acc[i][j][3] + bv.w;
            if (MODE == 0 || MODE == 2) {
                ushort4 h;
                h.x = f2bf(gelu_fast(v0)); h.y = f2bf(gelu_fast(v1));
                h.z = f2bf(gelu_fast(v2)); h.w = f2bf(gelu_fast(v3));
                *(ushort4*)&Hout[(size_t)(z * CAP + slot) * II + n0] = h;
            } else if (MODE == 1) {
                if (w != 0.f) {
                    float* dp = &dout[(size_t)tok * DD + n0];
                    atomicAdd(dp + 0, v0 * w);
                    atomicAdd(dp + 1, v1 * w);
                    atomicAdd(dp + 2, v2 * w);
                    atomicAdd(dp + 3, v3 * w);
                }
            } else { // MODE == 3
                if (ok3)
                    *(float4*)&dout[(size_t)tok * DD + n0] = make_float4(v0, v1, v2, v3);
            }
        }
    }
}

// ---------------------------------------------------------------------------
extern "C" void kernel_launch(void* const* d_in, const int* in_sizes, int n_in,
                              void* d_out, int out_size, void* d_ws, size_t ws_size,
                              hipStream_t stream) {
    const float* x   = (const float*)d_in[0];
    const float* Wr  = (const float*)d_in[1];
    const float* W1  = (const float*)d_in[2];
    const float* b1  = (const float*)d_in[3];
    const float* W2  = (const float*)d_in[4];
    const float* b2  = (const float*)d_in[5];
    const float* fw1 = (const float*)d_in[6];
    const float* fb1 = (const float*)d_in[7];
    const float* fw2 = (const float*)d_in[8];
    const float* fb2 = (const float*)d_in[9];
    float* out = (float*)d_out;

    char* ws = (char*)d_ws;
    size_t off = 0;
    auto alloc = [&](size_t bytes) -> void* {
        void* p = ws + off;
        off += (bytes + 255) & ~(size_t)255;
        return p;
    };
    unsigned short* W1t  = (unsigned short*)alloc((size_t)EE * DD * II * 2);
    unsigned short* W2t  = (unsigned short*)alloc((size_t)EE * II * DD * 2);
    unsigned short* fw1t = (unsigned short*)alloc((size_t)DD * II * 2);
    unsigned short* fw2t = (unsigned short*)alloc((size_t)II * DD * 2);
    unsigned short* xbf  = (unsigned short*)alloc((size_t)TT * DD * 2);
    int*   e0a   = (int*)alloc(TT * 4);
    int*   e1a   = (int*)alloc(TT * 4);
    float* w0a   = (float*)alloc(TT * 4);
    float* w1a   = (float*)alloc(TT * 4);
    int*   idxb  = (int*)alloc(EE * CAP * 4);
    float* wslb  = (float*)alloc(EE * CAP * 4);
    int*   fbidx = (int*)alloc(4 * CAP * 4);
    int*   counts = (int*)alloc(64);

    // H buffer: as many experts' worth as workspace allows (21 MB each)
    size_t perExpert = (size_t)CAP * II * 2;
    size_t remain = (ws_size > off) ? (ws_size - off) : 0;
    int G = (int)(remain / perExpert);
    if (G < 1) G = 1;
    if (G > EE) G = EE;
    unsigned short* H = (unsigned short*)(ws + off);

    hipMemsetAsync(d_out, 0, (size_t)TT * DD * sizeof(float), stream);

    cvt_x<<<TT * DD / (256 * 8), 256, 0, stream>>>(x, xbf);
    transpose_cvt<<<dim3(II / 32, DD / 32, EE), dim3(32, 8), 0, stream>>>(W1, W1t, DD, II);
    transpose_cvt<<<dim3(DD / 32, II / 32, EE), dim3(32, 8), 0, stream>>>(W2, W2t, II, DD);
    transpose_cvt<<<dim3(II / 32, DD / 32, 1),  dim3(32, 8), 0, stream>>>(fw1, fw1t, DD, II);
    transpose_cvt<<<dim3(DD / 32, II / 32, 1),  dim3(32, 8), 0, stream>>>(fw2, fw2t, II, DD);

    router_kernel<<<TT / 4, 256, 0, stream>>>(x, Wr, e0a, e1a, w0a, w1a);
    assign_kernel<<<1, 1024, 0, stream>>>(e0a, e1a, w0a, w1a, idxb, wslb, fbidx, counts);

    for (int eb = 0; eb < EE; eb += G) {
        int g = (EE - eb < G) ? (EE - eb) : G;
        gemm_kernel<0><<<dim3(CAP / BM, II / BN, g), 256, 0, stream>>>(
            xbf, W1t, b1, H, nullptr, idxb, wslb, counts, eb, 0);
        gemm_kernel<1><<<dim3(CAP / BM, DD / BN, g), 256, 0, stream>>>(
            H, W2t, b2, nullptr, out, idxb, wslb, counts, eb, 0);
    }
    // fallback FFN over overflow tokens only (n_fb expected 0 -> early exit)
    if (G >= 4) {
        gemm_kernel<2><<<dim3(CAP / BM, II / BN, 4), 256, 0, stream>>>(
            xbf, fw1t, fb1, H, nullptr, fbidx, nullptr, counts, 0, 0);
        gemm_kernel<3><<<dim3(CAP / BM, DD / BN, 4), 256, 0, stream>>>(
            H, fw2t, fb2, nullptr, out, fbidx, nullptr, counts, 0, 0);
    } else {
        for (int c = 0; c < 4; ++c) {
            gemm_kernel<2><<<dim3(CAP / BM, II / BN, 1), 256, 0, stream>>>(
                xbf, fw1t, fb1, H, nullptr, fbidx, nullptr, counts, 0, c * CAP);
            gemm_kernel<3><<<dim3(CAP / BM, DD / BN, 1), 256, 0, stream>>>(
                H, fw2t, fb2, nullptr, out, fbidx, nullptr, counts, 0, c * CAP);
        }
    }
    (void)in_sizes; (void)n_in; (void)out_size;
}